// Round 18
// baseline (354.547 us; speedup 1.0000x reference)
//
#include <hip/hip_runtime.h>
#include <hip/hip_bf16.h>
#include <cstdint>

typedef __bf16 bf16x8  __attribute__((ext_vector_type(8)));
typedef float  f32x16  __attribute__((ext_vector_type(16)));

struct alignas(4) us2 { unsigned short x, y; };
struct alignas(8) us4 { unsigned short x, y, z, w; };

__device__ __forceinline__ unsigned short f2bf(float f) {
    union { float f; unsigned u; } a; a.f = f;
    unsigned r = a.u + 0x7fffu + ((a.u >> 16) & 1u);   // round-to-nearest-even
    return (unsigned short)(r >> 16);
}

__device__ __forceinline__ void gl_lds16(const void* g, void* s) {
    __builtin_amdgcn_global_load_lds(
        (const __attribute__((address_space(1))) void*)g,
        (__attribute__((address_space(3))) void*)s, 16, 0, 0);
}

#define SCHEDB()  __builtin_amdgcn_sched_barrier(0)
#define SBAR()    do { SCHEDB(); __builtin_amdgcn_s_barrier(); SCHEDB(); } while (0)
#define WAITLG(N) do { asm volatile("s_waitcnt lgkmcnt(" #N ")" ::: "memory"); SCHEDB(); } while (0)
#define WAITVM(N) do { asm volatile("s_waitcnt vmcnt(" #N ")" ::: "memory"); SCHEDB(); } while (0)

// C = A(MxK) @ W(NxK)^T, bf16 in, fp32 acc. 256x256 tile, 8 waves (2Mx4N).
// R18: 32x32x16 MFMA (ceiling 2495 vs 2176 TF, half the instruction count)
// on the UNCHANGED R13 schedule (best of 13 variants: 44.5% MfmaUtil).
// Fragments: A/B frag = 16B/lane at row base+(lane&31), k-chunk c=kb/8+(lane>>5);
// with the R3 swizzle (chunk pos ^= (row>>1)&3) the 64-lane b128 access is
// exactly 8-per-bank = the b128 floor (0 extra conflicts, verified by hand).
// C/D [m74/m101]: col = lane&31, row = (r&3)+8*(r>>2)+4*(lane>>5), r in 0..15.
// Ring of 4 K-32 half-slots (A 16KB + B 16KB, 128KB). Stage h+3 during h.
// Per half: WAITVM(4) [cert stage(h+1)] -> SBAR -> issue cF(6, kb=16 slot h)
// -> WAITLG(6) [pF ready, cF floats; DS retires in-order] -> 8 MFMA (kb=0)
// -> issue nF(6, kb=0 slot h+1) + stage(h+3) -> WAITLG(6) [cF ready, nF floats]
// -> 8 MFMA (kb=16). Ping-pong pF/nF sets (R15).
// EPI 0: outb = bf16(gelu_exact(acc+bias)) ; EPI 1: outf = acc+bias ;
// EPI 2: fused coupling, W3 interleaved by 32-col blocks (s-block | t-block):
//   lane holds (s_j,t_j) in nf=0/1 of the same lane -> no shuffles for the
//   update; 32-lane xor-reduce for log_det.
template<int EPI, int K, int N>
__global__ __launch_bounds__(512, 2)
void gemm256(const unsigned short* __restrict__ A,
             const unsigned short* __restrict__ W,
             const float* __restrict__ bias,
             unsigned short* __restrict__ outb,
             float* __restrict__ outf,
             const float* __restrict__ zin,
             float* __restrict__ ldout)
{
    extern __shared__ char smem[];
    constexpr int NH = K / 32;           // number of K-32 halves (16 or 64)
    constexpr int GX = N / 256;

    const int tid  = threadIdx.x;
    const int lane = tid & 63;
    const int wv   = tid >> 6;           // 0..7
    const int wr   = wv >> 2, wc = wv & 3;

    // T1: bijective XCD swizzle (nwg divisible by 8 for all our shapes)
    const int bid = blockIdx.y * GX + blockIdx.x;
    const int nwg = GX * (int)gridDim.y;
    const int swz = (bid & 7) * (nwg >> 3) + (bid >> 3);
    const size_t row0 = (size_t)(swz / GX) * 256;
    const size_t col0 = (size_t)(swz % GX) * 256;

    // LDS: A ring = 4 x 16KB at +0 ; B ring = 4 x 16KB at +65536.
    // Half-slot: 256 rows x 64B. Chunk c (16B): row c>>2, pos c&3, holds
    // src k-chunk (c&3) ^ ((row>>1)&3)   [R3 swizzle, 0-conflict]
    const int cse = (((tid & 3) ^ ((tid >> 3) & 3)) << 3);  // src elem offset
    const unsigned short* ag = A + (row0 + (tid >> 2)) * (size_t)K + cse;
    const unsigned short* bg = W + (col0 + (tid >> 2)) * (size_t)K + cse;

    auto stage = [&](int hh) {           // 4 x gl_lds (A j0,j1 ; B j0,j1)
        char* dA = smem + (hh & 3) * 16384 + tid * 16;
        char* dB = dA + 65536;
        const unsigned short* a = ag + (size_t)hh * 32;
        const unsigned short* b = bg + (size_t)hh * 32;
        gl_lds16(a,                     dA);
        gl_lds16(a + (size_t)128 * K,   dA + 8192);
        gl_lds16(b,                     dB);
        gl_lds16(b + (size_t)128 * K,   dB + 8192);
    };

    // 32x32 fragment reads: byte = (rowbase+ln31)*64 + ((c ^ q)<<4),
    // c = kb/8 + khi ; q = (ln31>>1)&3 (lane-const). kb=16 flips bit1: ^32.
    const int ln31 = lane & 31;
    const int khi  = lane >> 5;
    const int xo0  = (((khi) ^ ((ln31 >> 1) & 3)) << 4);    // kb=0 slot offset
    const int arow = wr * 128 + ln31;                       // + mf*32 (mf 0..3)
    const int brow = wc * 64 + ln31;                        // + nf*32 (nf 0..1)

#define LD32(base, rowb, X) (*(const bf16x8*)((base) + (size_t)(rowb) * 64 + (xo0 ^ (X))))

    f32x16 acc[4][2] = {};
    bf16x8 F0[6], F1[6];   // ping-pong: [0..3]=A mf0..3, [4..5]=B nf0..1 (kb=0)

    // prologue: stage halves 0,1,2 ; certify stage(0) ; read slot-0 kb=0 set
    stage(0); stage(1); stage(2);
    WAITVM(8);                           // stage(0) landed (1,2 in flight)
    SBAR();
#pragma unroll
    for (int mf = 0; mf < 4; ++mf) F0[mf] = LD32(smem, arow + mf * 32, 0);
#pragma unroll
    for (int nf = 0; nf < 2; ++nf) F0[4 + nf] = LD32(smem + 65536, brow + nf * 32, 0);

    // one K-32 half: consume pF (kb=0, prefetched) + cF (kb=16, same half);
    // prefetch nF (kb=0 of slot h+1).
    auto half_body = [&](int h, bf16x8 (&pF)[6], bf16x8 (&nF)[6]) {
        const char* cA  = smem + (h & 3) * 16384;
        const char* cB  = cA + 65536;
        const char* cAn = smem + ((h + 1) & 3) * 16384;
        const char* cBn = cAn + 65536;

        if (h <= NH - 3) WAITVM(4);      // certify stage(h+1); counted
        else             WAITVM(0);
        SBAR();

        bf16x8 cF[6];
#pragma unroll
        for (int mf = 0; mf < 4; ++mf) cF[mf] = LD32(cA, arow + mf * 32, 32);
#pragma unroll
        for (int nf = 0; nf < 2; ++nf) cF[4 + nf] = LD32(cB, brow + nf * 32, 32);

        WAITLG(6);                       // pF certified (oldest 6); cF floats
        __builtin_amdgcn_s_setprio(1);
#pragma unroll
        for (int mf = 0; mf < 4; ++mf)
#pragma unroll
            for (int nf = 0; nf < 2; ++nf)
                acc[mf][nf] = __builtin_amdgcn_mfma_f32_32x32x16_bf16(
                    pF[mf], pF[4 + nf], acc[mf][nf], 0, 0, 0);
        __builtin_amdgcn_s_setprio(0);

        if (h + 1 < NH) {
#pragma unroll
            for (int mf = 0; mf < 4; ++mf) nF[mf] = LD32(cAn, arow + mf * 32, 0);
#pragma unroll
            for (int nf = 0; nf < 2; ++nf) nF[4 + nf] = LD32(cBn, brow + nf * 32, 0);
            SCHEDB();
        }
        if (h + 3 < NH) stage(h + 3);

        if (h + 1 < NH) WAITLG(6);       // cF certified; nF floats
        else            WAITLG(0);
        __builtin_amdgcn_s_setprio(1);
#pragma unroll
        for (int mf = 0; mf < 4; ++mf)
#pragma unroll
            for (int nf = 0; nf < 2; ++nf)
                acc[mf][nf] = __builtin_amdgcn_mfma_f32_32x32x16_bf16(
                    cF[mf], cF[4 + nf], acc[mf][nf], 0, 0, 0);
        __builtin_amdgcn_s_setprio(0);
    };

    for (int h = 0; h < NH; h += 2) {
        half_body(h,     F0, F1);        // consume set0, fill set1
        half_body(h + 1, F1, F0);        // consume set1, fill set0
    }
#undef LD32

    // epilogue: D layout col = lane&31, row = (r&3)+8*(r>>2)+4*khi
    float bv[2];
#pragma unroll
    for (int nf = 0; nf < 2; ++nf) bv[nf] = bias[col0 + wc * 64 + nf * 32 + ln31];

    if (EPI == 2) {
        // W interleaved by 32-col blocks: nf=0 -> s_j, nf=1 -> t_j, same lane.
        const float2* zin2 = (const float2*)zin;
        float2*       out2 = (float2*)outf;
        const size_t jj = (col0 >> 1) + wc * 32 + ln31;
#pragma unroll
        for (int mf = 0; mf < 4; ++mf) {
#pragma unroll
            for (int r = 0; r < 16; ++r) {
                const size_t row = row0 + wr * 128 + mf * 32
                                 + (r & 3) + 8 * (r >> 2) + 4 * khi;
                float s = acc[mf][0][r] + bv[0];
                float t = acc[mf][1][r] + bv[1];
                float2 zv = zin2[row * 512 + jj];
                float2 o; o.x = zv.x; o.y = zv.y * __expf(s) + t;
                out2[row * 512 + jj] = o;
                float sv = s;
                sv += __shfl_xor(sv, 1, 64);
                sv += __shfl_xor(sv, 2, 64);
                sv += __shfl_xor(sv, 4, 64);
                sv += __shfl_xor(sv, 8, 64);
                sv += __shfl_xor(sv, 16, 64);
                if (ln31 == 0) atomicAdd(&ldout[row], sv);
            }
        }
    } else {
#pragma unroll
        for (int mf = 0; mf < 4; ++mf) {
#pragma unroll
            for (int r = 0; r < 16; ++r) {
                const size_t row = row0 + wr * 128 + mf * 32
                                 + (r & 3) + 8 * (r >> 2) + 4 * khi;
#pragma unroll
                for (int nf = 0; nf < 2; ++nf) {
                    const size_t col = col0 + wc * 64 + nf * 32 + ln31;
                    float v = acc[mf][nf][r] + bv[nf];
                    if (EPI == 0) {
                        float g = 0.5f * v * (1.0f + erff(v * 0.70710678118654752f));
                        outb[row * N + col] = f2bf(g);
                    } else {
                        outf[row * N + col] = v;
                    }
                }
            }
        }
    }
}

// One fused prep pass: W1/W2 cvt, W3 interleave-by-32 cvt, pack_even, b3i, ldout.
__global__ void prep_all(const float* __restrict__ W1, const float* __restrict__ W2,
                         const float* __restrict__ W3, const float* __restrict__ b3,
                         const float* __restrict__ z,  const float* __restrict__ ld,
                         unsigned short* __restrict__ w1b, unsigned short* __restrict__ w2b,
                         unsigned short* __restrict__ w3i, float* __restrict__ b3i,
                         unsigned short* __restrict__ zm,  float* __restrict__ ldout)
{
    constexpr int N1 = 2048 * 512 / 4;
    constexpr int N2 = 2048 * 2048 / 4;
    constexpr int N3 = 1024 * 2048 / 4;
    constexpr int N4 = 16384 * 1024 / 4;
    constexpr int N5 = 1024;
    constexpr int N6 = 16384;
    constexpr int TOT = N1 + N2 + N3 + N4 + N5 + N6;
    const int stride = gridDim.x * blockDim.x;
    for (int i = blockIdx.x * blockDim.x + threadIdx.x; i < TOT; i += stride) {
        int j = i;
        if (j < N1) {
            float4 v = ((const float4*)W1)[j];
            ((us4*)w1b)[j] = us4{ f2bf(v.x), f2bf(v.y), f2bf(v.z), f2bf(v.w) };
            continue;
        }
        j -= N1;
        if (j < N2) {
            float4 v = ((const float4*)W2)[j];
            ((us4*)w2b)[j] = us4{ f2bf(v.x), f2bf(v.y), f2bf(v.z), f2bf(v.w) };
            continue;
        }
        j -= N2;
        if (j < N3) {
            int row = j >> 9, c4 = j & 511;
            int q = row >> 6, u = row & 63;
            int srcrow = (u < 32) ? (q * 32 + u) : (512 + q * 32 + u - 32);
            float4 v = ((const float4*)W3)[(size_t)srcrow * 512 + c4];
            ((us4*)w3i)[j] = us4{ f2bf(v.x), f2bf(v.y), f2bf(v.z), f2bf(v.w) };
            continue;
        }
        j -= N3;
        if (j < N4) {
            float4 v = ((const float4*)z)[j];
            ((us2*)zm)[j] = us2{ f2bf(v.x), f2bf(v.z) };
            continue;
        }
        j -= N4;
        if (j < N5) {
            int q = j >> 6, u = j & 63;
            b3i[j] = b3[(u < 32) ? (q * 32 + u) : (512 + q * 32 + u - 32)];
            continue;
        }
        j -= N5;
        ldout[j] = ld[j];
    }
}

extern "C" void kernel_launch(void* const* d_in, const int* in_sizes, int n_in,
                              void* d_out, int out_size, void* d_ws, size_t ws_size,
                              hipStream_t stream)
{
    const float* z  = (const float*)d_in[0];
    const float* ld = (const float*)d_in[1];
    const float* W1 = (const float*)d_in[2];
    const float* b1 = (const float*)d_in[3];
    const float* W2 = (const float*)d_in[4];
    const float* b2 = (const float*)d_in[5];
    const float* W3 = (const float*)d_in[6];
    const float* b3 = (const float*)d_in[7];

    float* out   = (float*)d_out;
    float* zout  = out;
    float* ldout = out + (size_t)16384 * 1024;

    char* w = (char*)d_ws;
    unsigned short* zm  = (unsigned short*)w; w += (size_t)16384 * 512 * 2;
    unsigned short* w1b = (unsigned short*)w; w += (size_t)2048 * 512 * 2;
    unsigned short* w2b = (unsigned short*)w; w += (size_t)2048 * 2048 * 2;
    unsigned short* w3i = (unsigned short*)w; w += (size_t)1024 * 2048 * 2;
    unsigned short* h1  = (unsigned short*)w; w += (size_t)16384 * 2048 * 2;
    unsigned short* h2  = (unsigned short*)w; w += (size_t)16384 * 2048 * 2;
    float*          b3i = (float*)w;          w += 1024 * 4;

    (void)hipFuncSetAttribute((const void*)&gemm256<0, 512,  2048>,
                              hipFuncAttributeMaxDynamicSharedMemorySize, 131072);
    (void)hipFuncSetAttribute((const void*)&gemm256<0, 2048, 2048>,
                              hipFuncAttributeMaxDynamicSharedMemorySize, 131072);
    (void)hipFuncSetAttribute((const void*)&gemm256<2, 2048, 1024>,
                              hipFuncAttributeMaxDynamicSharedMemorySize, 131072);

    prep_all<<<2048, 256, 0, stream>>>(W1, W2, W3, b3, z, ld,
                                       w1b, w2b, w3i, b3i, zm, ldout);

    gemm256<0, 512,  2048><<<dim3(8, 64), 512, 131072, stream>>>(zm, w1b, b1, h1, nullptr, nullptr, nullptr);
    gemm256<0, 2048, 2048><<<dim3(8, 64), 512, 131072, stream>>>(h1, w2b, b2, h2, nullptr, nullptr, nullptr);
    gemm256<2, 2048, 1024><<<dim3(4, 64), 512, 131072, stream>>>(h2, w3i, b3i, nullptr, zout, z, ldout);
}

// Round 19
// 351.614 us; speedup vs baseline: 1.0083x; 1.0083x over previous
//
#include <hip/hip_runtime.h>
#include <hip/hip_bf16.h>
#include <cstdint>

typedef __bf16 bf16x8  __attribute__((ext_vector_type(8)));
typedef float  f32x16  __attribute__((ext_vector_type(16)));

struct alignas(4) us2 { unsigned short x, y; };
struct alignas(8) us4 { unsigned short x, y, z, w; };

__device__ __forceinline__ unsigned short f2bf(float f) {
    union { float f; unsigned u; } a; a.f = f;
    unsigned r = a.u + 0x7fffu + ((a.u >> 16) & 1u);   // round-to-nearest-even
    return (unsigned short)(r >> 16);
}

__device__ __forceinline__ void gl_lds16(const void* g, void* s) {
    __builtin_amdgcn_global_load_lds(
        (const __attribute__((address_space(1))) void*)g,
        (__attribute__((address_space(3))) void*)s, 16, 0, 0);
}

#define SCHEDB()  __builtin_amdgcn_sched_barrier(0)
#define SBAR()    do { SCHEDB(); __builtin_amdgcn_s_barrier(); SCHEDB(); } while (0)
#define WAITLG(N) do { asm volatile("s_waitcnt lgkmcnt(" #N ")" ::: "memory"); SCHEDB(); } while (0)
#define WAITVM(N) do { asm volatile("s_waitcnt vmcnt(" #N ")" ::: "memory"); SCHEDB(); } while (0)

// C = A(MxK) @ W(NxK)^T, bf16 in, fp32 acc. 256x256 tile, 8 waves (2Mx4N).
// R19 = R18 (32x32x16 MFMA, R13 schedule) with the swizzle FIXED for 32-row
// fragments: stored chunk pos p = c ^ swz(row), swz(row)=((row>>1)&3)^((row>>3)&3).
// R18's swz used only row bits[2:1] -> lanes l,l+8,l+16,l+24 same bank = 4-way
// conflict (measured 1.26e7, the R2/R9 signature). With bit[3] folded in, any
// 16 consecutive lanes hit each (bank-pair,slot) combo exactly 2x = free (m136).
// Read side: rowbase multiples of 32 contribute 0 -> xo is lane-constant.
// Staging: cse = ((tid&3) ^ ((tid>>3)&3) ^ ((tid>>5)&3)) << 3 (row+128 invariant).
// C/D [m74/m101]: col = lane&31, row = (r&3)+8*(r>>2)+4*(lane>>5), r in 0..15.
// Ring of 4 K-32 half-slots (A 16KB + B 16KB, 128KB). Stage h+3 during h.
// Per half: WAITVM(4) -> SBAR -> issue cF(6, kb=16) -> WAITLG(6) -> 8 MFMA(kb=0)
// -> issue nF(6, slot h+1 kb=0) + stage(h+3) -> WAITLG(6) -> 8 MFMA(kb=16).
// EPI 0: outb = bf16(gelu_exact(acc+bias)) ; EPI 1: outf = acc+bias ;
// EPI 2: fused coupling, W3 interleaved by 32-col blocks (s-block | t-block).
template<int EPI, int K, int N>
__global__ __launch_bounds__(512, 2)
void gemm256(const unsigned short* __restrict__ A,
             const unsigned short* __restrict__ W,
             const float* __restrict__ bias,
             unsigned short* __restrict__ outb,
             float* __restrict__ outf,
             const float* __restrict__ zin,
             float* __restrict__ ldout)
{
    extern __shared__ char smem[];
    constexpr int NH = K / 32;           // number of K-32 halves (16 or 64)
    constexpr int GX = N / 256;

    const int tid  = threadIdx.x;
    const int lane = tid & 63;
    const int wv   = tid >> 6;           // 0..7
    const int wr   = wv >> 2, wc = wv & 3;

    // T1: bijective XCD swizzle (nwg divisible by 8 for all our shapes)
    const int bid = blockIdx.y * GX + blockIdx.x;
    const int nwg = GX * (int)gridDim.y;
    const int swz = (bid & 7) * (nwg >> 3) + (bid >> 3);
    const size_t row0 = (size_t)(swz / GX) * 256;
    const size_t col0 = (size_t)(swz % GX) * 256;

    // LDS: A ring = 4 x 16KB at +0 ; B ring = 4 x 16KB at +65536.
    // Half-slot: 256 rows x 64B. Chunk c (16B): row c>>2, pos c&3, holds
    // src k-chunk (c&3) ^ ((row>>1)&3) ^ ((row>>3)&3)   [R19 swizzle]
    const int cse = (((tid & 3) ^ ((tid >> 3) & 3) ^ ((tid >> 5) & 3)) << 3);
    const unsigned short* ag = A + (row0 + (tid >> 2)) * (size_t)K + cse;
    const unsigned short* bg = W + (col0 + (tid >> 2)) * (size_t)K + cse;

    auto stage = [&](int hh) {           // 4 x gl_lds (A j0,j1 ; B j0,j1)
        char* dA = smem + (hh & 3) * 16384 + tid * 16;
        char* dB = dA + 65536;
        const unsigned short* a = ag + (size_t)hh * 32;
        const unsigned short* b = bg + (size_t)hh * 32;
        gl_lds16(a,                     dA);
        gl_lds16(a + (size_t)128 * K,   dA + 8192);
        gl_lds16(b,                     dB);
        gl_lds16(b + (size_t)128 * K,   dB + 8192);
    };

    // 32x32 fragment reads: byte = (rowbase+ln31)*64 + ((c ^ swz(ln31))<<4),
    // c = kb/8 + khi ; swz(ln31) = ((ln31>>1)&3)^((ln31>>3)&3). kb=16: ^32.
    const int ln31 = lane & 31;
    const int khi  = lane >> 5;
    const int xo0  = ((khi ^ ((ln31 >> 1) & 3) ^ ((ln31 >> 3) & 3)) << 4);
    const int arow = wr * 128 + ln31;                       // + mf*32 (mf 0..3)
    const int brow = wc * 64 + ln31;                        // + nf*32 (nf 0..1)

#define LD32(base, rowb, X) (*(const bf16x8*)((base) + (size_t)(rowb) * 64 + (xo0 ^ (X))))

    f32x16 acc[4][2] = {};
    bf16x8 F0[6], F1[6];   // ping-pong: [0..3]=A mf0..3, [4..5]=B nf0..1 (kb=0)

    // prologue: stage halves 0,1,2 ; certify stage(0) ; read slot-0 kb=0 set
    stage(0); stage(1); stage(2);
    WAITVM(8);                           // stage(0) landed (1,2 in flight)
    SBAR();
#pragma unroll
    for (int mf = 0; mf < 4; ++mf) F0[mf] = LD32(smem, arow + mf * 32, 0);
#pragma unroll
    for (int nf = 0; nf < 2; ++nf) F0[4 + nf] = LD32(smem + 65536, brow + nf * 32, 0);

    // one K-32 half: consume pF (kb=0, prefetched) + cF (kb=16, same half);
    // prefetch nF (kb=0 of slot h+1).
    auto half_body = [&](int h, bf16x8 (&pF)[6], bf16x8 (&nF)[6]) {
        const char* cA  = smem + (h & 3) * 16384;
        const char* cB  = cA + 65536;
        const char* cAn = smem + ((h + 1) & 3) * 16384;
        const char* cBn = cAn + 65536;

        if (h <= NH - 3) WAITVM(4);      // certify stage(h+1); counted
        else             WAITVM(0);
        SBAR();

        bf16x8 cF[6];
#pragma unroll
        for (int mf = 0; mf < 4; ++mf) cF[mf] = LD32(cA, arow + mf * 32, 32);
#pragma unroll
        for (int nf = 0; nf < 2; ++nf) cF[4 + nf] = LD32(cB, brow + nf * 32, 32);

        WAITLG(6);                       // pF certified (oldest 6); cF floats
        __builtin_amdgcn_s_setprio(1);
#pragma unroll
        for (int mf = 0; mf < 4; ++mf)
#pragma unroll
            for (int nf = 0; nf < 2; ++nf)
                acc[mf][nf] = __builtin_amdgcn_mfma_f32_32x32x16_bf16(
                    pF[mf], pF[4 + nf], acc[mf][nf], 0, 0, 0);
        __builtin_amdgcn_s_setprio(0);

        if (h + 1 < NH) {
#pragma unroll
            for (int mf = 0; mf < 4; ++mf) nF[mf] = LD32(cAn, arow + mf * 32, 0);
#pragma unroll
            for (int nf = 0; nf < 2; ++nf) nF[4 + nf] = LD32(cBn, brow + nf * 32, 0);
            SCHEDB();
        }
        if (h + 3 < NH) stage(h + 3);

        if (h + 1 < NH) WAITLG(6);       // cF certified; nF floats
        else            WAITLG(0);
        __builtin_amdgcn_s_setprio(1);
#pragma unroll
        for (int mf = 0; mf < 4; ++mf)
#pragma unroll
            for (int nf = 0; nf < 2; ++nf)
                acc[mf][nf] = __builtin_amdgcn_mfma_f32_32x32x16_bf16(
                    cF[mf], cF[4 + nf], acc[mf][nf], 0, 0, 0);
        __builtin_amdgcn_s_setprio(0);
    };

    for (int h = 0; h < NH; h += 2) {
        half_body(h,     F0, F1);        // consume set0, fill set1
        half_body(h + 1, F1, F0);        // consume set1, fill set0
    }
#undef LD32

    // epilogue: D layout col = lane&31, row = (r&3)+8*(r>>2)+4*khi
    float bv[2];
#pragma unroll
    for (int nf = 0; nf < 2; ++nf) bv[nf] = bias[col0 + wc * 64 + nf * 32 + ln31];

    if (EPI == 2) {
        // W interleaved by 32-col blocks: nf=0 -> s_j, nf=1 -> t_j, same lane.
        const float2* zin2 = (const float2*)zin;
        float2*       out2 = (float2*)outf;
        const size_t jj = (col0 >> 1) + wc * 32 + ln31;
#pragma unroll
        for (int mf = 0; mf < 4; ++mf) {
#pragma unroll
            for (int r = 0; r < 16; ++r) {
                const size_t row = row0 + wr * 128 + mf * 32
                                 + (r & 3) + 8 * (r >> 2) + 4 * khi;
                float s = acc[mf][0][r] + bv[0];
                float t = acc[mf][1][r] + bv[1];
                float2 zv = zin2[row * 512 + jj];
                float2 o; o.x = zv.x; o.y = zv.y * __expf(s) + t;
                out2[row * 512 + jj] = o;
                float sv = s;
                sv += __shfl_xor(sv, 1, 64);
                sv += __shfl_xor(sv, 2, 64);
                sv += __shfl_xor(sv, 4, 64);
                sv += __shfl_xor(sv, 8, 64);
                sv += __shfl_xor(sv, 16, 64);
                if (ln31 == 0) atomicAdd(&ldout[row], sv);
            }
        }
    } else {
#pragma unroll
        for (int mf = 0; mf < 4; ++mf) {
#pragma unroll
            for (int r = 0; r < 16; ++r) {
                const size_t row = row0 + wr * 128 + mf * 32
                                 + (r & 3) + 8 * (r >> 2) + 4 * khi;
#pragma unroll
                for (int nf = 0; nf < 2; ++nf) {
                    const size_t col = col0 + wc * 64 + nf * 32 + ln31;
                    float v = acc[mf][nf][r] + bv[nf];
                    if (EPI == 0) {
                        float g = 0.5f * v * (1.0f + erff(v * 0.70710678118654752f));
                        outb[row * N + col] = f2bf(g);
                    } else {
                        outf[row * N + col] = v;
                    }
                }
            }
        }
    }
}

// One fused prep pass: W1/W2 cvt, W3 interleave-by-32 cvt, pack_even, b3i, ldout.
__global__ void prep_all(const float* __restrict__ W1, const float* __restrict__ W2,
                         const float* __restrict__ W3, const float* __restrict__ b3,
                         const float* __restrict__ z,  const float* __restrict__ ld,
                         unsigned short* __restrict__ w1b, unsigned short* __restrict__ w2b,
                         unsigned short* __restrict__ w3i, float* __restrict__ b3i,
                         unsigned short* __restrict__ zm,  float* __restrict__ ldout)
{
    constexpr int N1 = 2048 * 512 / 4;
    constexpr int N2 = 2048 * 2048 / 4;
    constexpr int N3 = 1024 * 2048 / 4;
    constexpr int N4 = 16384 * 1024 / 4;
    constexpr int N5 = 1024;
    constexpr int N6 = 16384;
    constexpr int TOT = N1 + N2 + N3 + N4 + N5 + N6;
    const int stride = gridDim.x * blockDim.x;
    for (int i = blockIdx.x * blockDim.x + threadIdx.x; i < TOT; i += stride) {
        int j = i;
        if (j < N1) {
            float4 v = ((const float4*)W1)[j];
            ((us4*)w1b)[j] = us4{ f2bf(v.x), f2bf(v.y), f2bf(v.z), f2bf(v.w) };
            continue;
        }
        j -= N1;
        if (j < N2) {
            float4 v = ((const float4*)W2)[j];
            ((us4*)w2b)[j] = us4{ f2bf(v.x), f2bf(v.y), f2bf(v.z), f2bf(v.w) };
            continue;
        }
        j -= N2;
        if (j < N3) {
            int row = j >> 9, c4 = j & 511;
            int q = row >> 6, u = row & 63;
            int srcrow = (u < 32) ? (q * 32 + u) : (512 + q * 32 + u - 32);
            float4 v = ((const float4*)W3)[(size_t)srcrow * 512 + c4];
            ((us4*)w3i)[j] = us4{ f2bf(v.x), f2bf(v.y), f2bf(v.z), f2bf(v.w) };
            continue;
        }
        j -= N3;
        if (j < N4) {
            float4 v = ((const float4*)z)[j];
            ((us2*)zm)[j] = us2{ f2bf(v.x), f2bf(v.z) };
            continue;
        }
        j -= N4;
        if (j < N5) {
            int q = j >> 6, u = j & 63;
            b3i[j] = b3[(u < 32) ? (q * 32 + u) : (512 + q * 32 + u - 32)];
            continue;
        }
        j -= N5;
        ldout[j] = ld[j];
    }
}

extern "C" void kernel_launch(void* const* d_in, const int* in_sizes, int n_in,
                              void* d_out, int out_size, void* d_ws, size_t ws_size,
                              hipStream_t stream)
{
    const float* z  = (const float*)d_in[0];
    const float* ld = (const float*)d_in[1];
    const float* W1 = (const float*)d_in[2];
    const float* b1 = (const float*)d_in[3];
    const float* W2 = (const float*)d_in[4];
    const float* b2 = (const float*)d_in[5];
    const float* W3 = (const float*)d_in[6];
    const float* b3 = (const float*)d_in[7];

    float* out   = (float*)d_out;
    float* zout  = out;
    float* ldout = out + (size_t)16384 * 1024;

    char* w = (char*)d_ws;
    unsigned short* zm  = (unsigned short*)w; w += (size_t)16384 * 512 * 2;
    unsigned short* w1b = (unsigned short*)w; w += (size_t)2048 * 512 * 2;
    unsigned short* w2b = (unsigned short*)w; w += (size_t)2048 * 2048 * 2;
    unsigned short* w3i = (unsigned short*)w; w += (size_t)1024 * 2048 * 2;
    unsigned short* h1  = (unsigned short*)w; w += (size_t)16384 * 2048 * 2;
    unsigned short* h2  = (unsigned short*)w; w += (size_t)16384 * 2048 * 2;
    float*          b3i = (float*)w;          w += 1024 * 4;

    (void)hipFuncSetAttribute((const void*)&gemm256<0, 512,  2048>,
                              hipFuncAttributeMaxDynamicSharedMemorySize, 131072);
    (void)hipFuncSetAttribute((const void*)&gemm256<0, 2048, 2048>,
                              hipFuncAttributeMaxDynamicSharedMemorySize, 131072);
    (void)hipFuncSetAttribute((const void*)&gemm256<2, 2048, 1024>,
                              hipFuncAttributeMaxDynamicSharedMemorySize, 131072);

    prep_all<<<2048, 256, 0, stream>>>(W1, W2, W3, b3, z, ld,
                                       w1b, w2b, w3i, b3i, zm, ldout);

    gemm256<0, 512,  2048><<<dim3(8, 64), 512, 131072, stream>>>(zm, w1b, b1, h1, nullptr, nullptr, nullptr);
    gemm256<0, 2048, 2048><<<dim3(8, 64), 512, 131072, stream>>>(h1, w2b, b2, h2, nullptr, nullptr, nullptr);
    gemm256<2, 2048, 1024><<<dim3(4, 64), 512, 131072, stream>>>(h2, w3i, b3i, nullptr, zout, z, ldout);
}

// Round 20
// 330.347 us; speedup vs baseline: 1.0733x; 1.0644x over previous
//
#include <hip/hip_runtime.h>
#include <hip/hip_bf16.h>
#include <cstdint>

typedef __bf16 bf16x8 __attribute__((ext_vector_type(8)));
typedef float  f32x4  __attribute__((ext_vector_type(4)));

struct alignas(4) us2 { unsigned short x, y; };
struct alignas(8) us4 { unsigned short x, y, z, w; };

__device__ __forceinline__ unsigned short f2bf(float f) {
    union { float f; unsigned u; } a; a.f = f;
    unsigned r = a.u + 0x7fffu + ((a.u >> 16) & 1u);   // round-to-nearest-even
    return (unsigned short)(r >> 16);
}

__device__ __forceinline__ void gl_lds16(const void* g, void* s) {
    __builtin_amdgcn_global_load_lds(
        (const __attribute__((address_space(1))) void*)g,
        (__attribute__((address_space(3))) void*)s, 16, 0, 0);
}

#define SCHEDB()  __builtin_amdgcn_sched_barrier(0)
#define SBAR()    do { SCHEDB(); __builtin_amdgcn_s_barrier(); SCHEDB(); } while (0)
#define WAITLG(N) do { asm volatile("s_waitcnt lgkmcnt(" #N ")" ::: "memory"); SCHEDB(); } while (0)
#define WAITVM(N) do { asm volatile("s_waitcnt vmcnt(" #N ")" ::: "memory"); SCHEDB(); } while (0)

// C = A(MxK) @ W(NxK)^T, bf16 in, fp32 acc. 256x256 tile, 8 waves (2Mx4N).
// R20 = R13-exact K-loop (best of 19 rounds: GEMM2 146.5us, 0 conflicts,
// VGPR 108; the R18/R19 32x32 direction was refuted per pre-commit).
// Ring of 4 K-32 half-slots (A 16KB + B 16KB, 128KB). Stage h+3 during h.
// Per half: WAITVM(4) [cert thru stage(h+1)] -> SBAR -> issue aH(4) ->
// WAITLG(4) [pA/pB ready, aH floats] -> 16 MFMA -> prefetch nA/nB(8, slot h+1)
// + stage(h+3) -> WAITLG(8) [aH ready, prefetch floats] -> 16 MFMA -> rotate.
// Swizzle: R3-proven row-bits[2:1] XOR (0 conflicts measured).
// EPI 0: outb = bf16(gelu_exact(acc+bias)) ; EPI 1: outf = acc+bias.
// (R20: coupling epilogue EXTRACTED to finalize2 - GEMM3's fused epilogue was
//  fully exposed at 1-block/CU single-round occupancy; GEMM3 ran ~= GEMM2's
//  full wall with half the FLOPs.)
template<int EPI, int K, int N>
__global__ __launch_bounds__(512, 2)
void gemm256(const unsigned short* __restrict__ A,
             const unsigned short* __restrict__ W,
             const float* __restrict__ bias,
             unsigned short* __restrict__ outb,
             float* __restrict__ outf)
{
    extern __shared__ char smem[];
    constexpr int NH = K / 32;           // number of K-32 halves (16 or 64)
    constexpr int GX = N / 256;

    const int tid  = threadIdx.x;
    const int lane = tid & 63;
    const int wv   = tid >> 6;           // 0..7
    const int wr   = wv >> 2, wc = wv & 3;

    // T1: bijective XCD swizzle (nwg divisible by 8 for all our shapes)
    const int bid = blockIdx.y * GX + blockIdx.x;
    const int nwg = GX * (int)gridDim.y;
    const int swz = (bid & 7) * (nwg >> 3) + (bid >> 3);
    const size_t row0 = (size_t)(swz / GX) * 256;
    const size_t col0 = (size_t)(swz % GX) * 256;

    // LDS: A ring = 4 x 16KB at +0 ; B ring = 4 x 16KB at +65536.
    // Half-slot: 256 rows x 64B. Chunk c (16B): row c>>2, pos c&3, holds
    // src k-chunk (c&3) ^ ((row>>1)&3)   [R3 swizzle, 0-conflict]
    const int cse = (((tid & 3) ^ ((tid >> 3) & 3)) << 3);  // src elem offset
    const unsigned short* ag = A + (row0 + (tid >> 2)) * (size_t)K + cse;
    const unsigned short* bg = W + (col0 + (tid >> 2)) * (size_t)K + cse;

    auto stage = [&](int hh) {           // 4 x gl_lds (A j0,j1 ; B j0,j1)
        char* dA = smem + (hh & 3) * 16384 + tid * 16;
        char* dB = dA + 65536;
        const unsigned short* a = ag + (size_t)hh * 32;
        const unsigned short* b = bg + (size_t)hh * 32;
        gl_lds16(a,                     dA);
        gl_lds16(a + (size_t)128 * K,   dA + 8192);
        gl_lds16(b,                     dB);
        gl_lds16(b + (size_t)128 * K,   dB + 8192);
    };

    // fragment reads: byte = row*64 + ((lane>>4) ^ ((row>>1)&3))*16
    const int ln15 = lane & 15;
    const int xo   = (((lane >> 4) ^ ((ln15 >> 1) & 3)) << 4);
    const int arow = wr * 128 + ln15;                       // + mi*16 (mi 0..7)
    const int brow = wc * 64 + ln15;                        // + nf*16 (nf 0..3)

#define LD(base, row) (*(const bf16x8*)((base) + (size_t)(row) * 64 + xo))

    f32x4 acc[8][4] = {};
    bf16x8 pA[4], pB[4], nA[4], nB[4], aH[4];

    // prologue: stage halves 0,1,2 ; certify stage(0) ; prefetch slot-0 quad-1
    stage(0); stage(1); stage(2);
    WAITVM(8);                           // stage(0) landed (1,2 in flight)
    SBAR();
#pragma unroll
    for (int mf = 0; mf < 4; ++mf) pA[mf] = LD(smem, arow + mf * 16);
#pragma unroll
    for (int nf = 0; nf < 4; ++nf) pB[nf] = LD(smem + 65536, brow + nf * 16);

    for (int h = 0; h < NH; ++h) {
        const char* cA  = smem + (h & 3) * 16384;
        const char* cAn = smem + ((h + 1) & 3) * 16384;
        const char* cBn = cAn + 65536;

        // top-of-half: certify through stage(h+1) (counted; never drains
        // in steady state), then barrier -> slot h+1 write-certified block-wide.
        if (h <= NH - 3) WAITVM(4);
        else             WAITVM(0);
        SBAR();

        // issue aH (slot h, rows 64..127); pA/pB already in flight/landed
#pragma unroll
        for (int mf = 0; mf < 4; ++mf) aH[mf] = LD(cA, arow + 64 + mf * 16);
        WAITLG(4);                       // pA,pB certified; aH floats
        __builtin_amdgcn_s_setprio(1);
#pragma unroll
        for (int mf = 0; mf < 4; ++mf)
#pragma unroll
            for (int nf = 0; nf < 4; ++nf)
                acc[mf][nf] = __builtin_amdgcn_mfma_f32_16x16x32_bf16(
                    pA[mf], pB[nf], acc[mf][nf], 0, 0, 0);
        __builtin_amdgcn_s_setprio(0);

        // prefetch next half's quadrant-1 (slot h+1) + stage h+3
        if (h + 1 < NH) {
#pragma unroll
            for (int mf = 0; mf < 4; ++mf) nA[mf] = LD(cAn, arow + mf * 16);
#pragma unroll
            for (int nf = 0; nf < 4; ++nf) nB[nf] = LD(cBn, brow + nf * 16);
            SCHEDB();
        }
        if (h + 3 < NH) stage(h + 3);

        if (h + 1 < NH) WAITLG(8);       // aH certified; nA/nB float
        else            WAITLG(0);
        __builtin_amdgcn_s_setprio(1);
#pragma unroll
        for (int mf = 0; mf < 4; ++mf)
#pragma unroll
            for (int nf = 0; nf < 4; ++nf)
                acc[mf + 4][nf] = __builtin_amdgcn_mfma_f32_16x16x32_bf16(
                    aH[mf], pB[nf], acc[mf + 4][nf], 0, 0, 0);
        __builtin_amdgcn_s_setprio(0);

        // rotate (static indices, fully unrolled - no scratch)
#pragma unroll
        for (int i = 0; i < 4; ++i) { pA[i] = nA[i]; pB[i] = nB[i]; }
    }
#undef LD

    // epilogue: D layout col = lane&15, row = (lane>>4)*4 + reg
    const int lq = lane >> 4;
    float bv[4];
#pragma unroll
    for (int nf = 0; nf < 4; ++nf) bv[nf] = bias[col0 + wc * 64 + nf * 16 + ln15];

#pragma unroll
    for (int mi = 0; mi < 8; ++mi) {
#pragma unroll
        for (int r = 0; r < 4; ++r) {
            const size_t row = row0 + wr * 128 + mi * 16 + lq * 4 + r;
#pragma unroll
            for (int nf = 0; nf < 4; ++nf) {
                const size_t col = col0 + wc * 64 + nf * 16 + ln15;
                float v = acc[mi][nf][r] + bv[nf];
                if (EPI == 0) {
                    float g = 0.5f * v * (1.0f + erff(v * 0.70710678118654752f));
                    outb[row * N + col] = f2bf(g);
                } else {
                    outf[row * N + col] = v;
                }
            }
        }
    }
}

// Streaming coupling epilogue: one wave per 2 rows, fully coalesced.
// st[row][0..511]=s, [512..1023]=t (raw GEMM3 output, bias already added).
// z_out[:,2k]=z[:,2k]; z_out[:,2k+1]=z[:,2k+1]*exp(s_k)+t_k; ldout=ld+sum(s).
__global__ __launch_bounds__(256)
void finalize2(const float* __restrict__ st, const float* __restrict__ z,
               const float* __restrict__ ld, float* __restrict__ zout,
               float* __restrict__ ldout)
{
    const int lane = threadIdx.x & 63;
    const int wvi  = threadIdx.x >> 6;
    const int rb   = blockIdx.x * 8 + wvi * 2;
#pragma unroll
    for (int rr = 0; rr < 2; ++rr) {
        const int row = rb + rr;
        const float4* s4p = (const float4*)(st + (size_t)row * 1024);
        const float4* t4p = (const float4*)(st + (size_t)row * 1024 + 512);
        const float4* z4p = (const float4*)(z  + (size_t)row * 1024);
        float4*       o4p = (float4*)(zout + (size_t)row * 1024);
        float lsum = 0.f;
#pragma unroll
        for (int half = 0; half < 2; ++half) {
            const int i = lane + half * 64;      // float4-group 0..127 (k=4i..4i+3)
            float4 s = s4p[i];
            float4 t = t4p[i];
            float4 z0 = z4p[2 * i], z1 = z4p[2 * i + 1];
            float4 o0, o1;
            o0.x = z0.x; o0.y = z0.y * __expf(s.x) + t.x;
            o0.z = z0.z; o0.w = z0.w * __expf(s.y) + t.y;
            o1.x = z1.x; o1.y = z1.y * __expf(s.z) + t.z;
            o1.z = z1.z; o1.w = z1.w * __expf(s.w) + t.w;
            o4p[2 * i]     = o0;
            o4p[2 * i + 1] = o1;
            lsum += s.x + s.y + s.z + s.w;
        }
#pragma unroll
        for (int off = 32; off > 0; off >>= 1) lsum += __shfl_down(lsum, off, 64);
        if (lane == 0) ldout[row] = ld[row] + lsum;
    }
}

// One fused prep pass: W1/W2/W3 cvt + pack_even.
__global__ void prep_all(const float* __restrict__ W1, const float* __restrict__ W2,
                         const float* __restrict__ W3, const float* __restrict__ z,
                         unsigned short* __restrict__ w1b, unsigned short* __restrict__ w2b,
                         unsigned short* __restrict__ w3b, unsigned short* __restrict__ zm)
{
    constexpr int N1 = 2048 * 512 / 4;
    constexpr int N2 = 2048 * 2048 / 4;
    constexpr int N3 = 1024 * 2048 / 4;
    constexpr int N4 = 16384 * 1024 / 4;
    constexpr int TOT = N1 + N2 + N3 + N4;
    const int stride = gridDim.x * blockDim.x;
    for (int i = blockIdx.x * blockDim.x + threadIdx.x; i < TOT; i += stride) {
        int j = i;
        if (j < N1) {
            float4 v = ((const float4*)W1)[j];
            ((us4*)w1b)[j] = us4{ f2bf(v.x), f2bf(v.y), f2bf(v.z), f2bf(v.w) };
            continue;
        }
        j -= N1;
        if (j < N2) {
            float4 v = ((const float4*)W2)[j];
            ((us4*)w2b)[j] = us4{ f2bf(v.x), f2bf(v.y), f2bf(v.z), f2bf(v.w) };
            continue;
        }
        j -= N2;
        if (j < N3) {
            float4 v = ((const float4*)W3)[j];
            ((us4*)w3b)[j] = us4{ f2bf(v.x), f2bf(v.y), f2bf(v.z), f2bf(v.w) };
            continue;
        }
        j -= N3;
        float4 v = ((const float4*)z)[j];
        ((us2*)zm)[j] = us2{ f2bf(v.x), f2bf(v.z) };
    }
}

extern "C" void kernel_launch(void* const* d_in, const int* in_sizes, int n_in,
                              void* d_out, int out_size, void* d_ws, size_t ws_size,
                              hipStream_t stream)
{
    const float* z  = (const float*)d_in[0];
    const float* ld = (const float*)d_in[1];
    const float* W1 = (const float*)d_in[2];
    const float* b1 = (const float*)d_in[3];
    const float* W2 = (const float*)d_in[4];
    const float* b2 = (const float*)d_in[5];
    const float* W3 = (const float*)d_in[6];
    const float* b3 = (const float*)d_in[7];

    float* out   = (float*)d_out;
    float* zout  = out;
    float* ldout = out + (size_t)16384 * 1024;

    char* w = (char*)d_ws;
    unsigned short* zm  = (unsigned short*)w; w += (size_t)16384 * 512 * 2;
    unsigned short* w1b = (unsigned short*)w; w += (size_t)2048 * 512 * 2;
    unsigned short* w2b = (unsigned short*)w; w += (size_t)2048 * 2048 * 2;
    unsigned short* w3b = (unsigned short*)w; w += (size_t)1024 * 2048 * 2;
    unsigned short* h1  = (unsigned short*)w; w += (size_t)16384 * 2048 * 2;
    unsigned short* h2  = (unsigned short*)w; w += (size_t)16384 * 2048 * 2;
    // st reuses h1's region (dead after GEMM2): 16384*1024 fp32 = 64MB exact fit
    float* st = (float*)h1;

    (void)hipFuncSetAttribute((const void*)&gemm256<0, 512,  2048>,
                              hipFuncAttributeMaxDynamicSharedMemorySize, 131072);
    (void)hipFuncSetAttribute((const void*)&gemm256<0, 2048, 2048>,
                              hipFuncAttributeMaxDynamicSharedMemorySize, 131072);
    (void)hipFuncSetAttribute((const void*)&gemm256<1, 2048, 1024>,
                              hipFuncAttributeMaxDynamicSharedMemorySize, 131072);

    prep_all<<<2048, 256, 0, stream>>>(W1, W2, W3, z, w1b, w2b, w3b, zm);

    gemm256<0, 512,  2048><<<dim3(8, 64), 512, 131072, stream>>>(zm, w1b, b1, h1, nullptr);
    gemm256<0, 2048, 2048><<<dim3(8, 64), 512, 131072, stream>>>(h1, w2b, b2, h2, nullptr);
    gemm256<1, 2048, 1024><<<dim3(4, 64), 512, 131072, stream>>>(h2, w3b, b3, nullptr, st);

    finalize2<<<2048, 256, 0, stream>>>(st, z, ld, zout, ldout);
}

// Round 21
// 318.486 us; speedup vs baseline: 1.1132x; 1.0372x over previous
//
#include <hip/hip_runtime.h>
#include <hip/hip_bf16.h>
#include <cstdint>

typedef __bf16 bf16x8 __attribute__((ext_vector_type(8)));
typedef float  f32x4  __attribute__((ext_vector_type(4)));

struct alignas(4) us2 { unsigned short x, y; };
struct alignas(8) us4 { unsigned short x, y, z, w; };

__device__ __forceinline__ unsigned short f2bf(float f) {
    union { float f; unsigned u; } a; a.f = f;
    unsigned r = a.u + 0x7fffu + ((a.u >> 16) & 1u);   // round-to-nearest-even
    return (unsigned short)(r >> 16);
}

__device__ __forceinline__ void gl_lds16(const void* g, void* s) {
    __builtin_amdgcn_global_load_lds(
        (const __attribute__((address_space(1))) void*)g,
        (__attribute__((address_space(3))) void*)s, 16, 0, 0);
}

#define SCHEDB()  __builtin_amdgcn_sched_barrier(0)
#define SBAR()    do { SCHEDB(); __builtin_amdgcn_s_barrier(); SCHEDB(); } while (0)
#define WAITLG(N) do { asm volatile("s_waitcnt lgkmcnt(" #N ")" ::: "memory"); SCHEDB(); } while (0)
#define WAITVM(N) do { asm volatile("s_waitcnt vmcnt(" #N ")" ::: "memory"); SCHEDB(); } while (0)

// C = A(MxK) @ W(NxK)^T, bf16 in, fp32 acc. 256x256 tile, 8 waves (2Mx4N).
// SESSION-BEST configuration (R15, 316.06us measured; re-locked in R21):
// R13 deep read pipeline + period-2 register ping-pong.
// Ring of 4 K-32 half-slots (A 16KB + B 16KB, 128KB). Stage h+3 during h.
// Per half: WAITVM(4) [certify thru stage(h+1)] -> SBAR -> issue aH(4) ->
// WAITLG(4) [pA/pB ready, aH floats] -> 16 MFMA -> prefetch nA/nB(8, slot h+1)
// + stage(h+3) -> WAITLG(8) [aH ready, prefetch floats] -> 16 MFMA.
// Hazard (ring-4): in-flight reads target slots h,h+1; DMA writes (h+2),(h+3).
// Swizzle: R3-proven row-bits[2:1] XOR (0 conflicts measured).
// Refuted directions (do not revisit): 32x32x16 MFMA (R18/R19: unresolved 4-way
// conflicts), 2 blocks/CU (R6/R12: acc+operands ~236 unified regs > 128 cap),
// split coupling epilogue (R20: +14us), x4 unroll (R14: spill).
// EPI 0: outb = bf16(gelu_exact(acc+bias)) ; EPI 1: outf = acc+bias ;
// EPI 2: fused coupling, W3 interleaved by 16-col blocks (s-block | t-block).
template<int EPI, int K, int N>
__global__ __launch_bounds__(512, 2)
void gemm256(const unsigned short* __restrict__ A,
             const unsigned short* __restrict__ W,
             const float* __restrict__ bias,
             unsigned short* __restrict__ outb,
             float* __restrict__ outf,
             const float* __restrict__ zin,
             float* __restrict__ ldout)
{
    extern __shared__ char smem[];
    constexpr int NH = K / 32;           // number of K-32 halves (16 or 64)
    constexpr int GX = N / 256;
    static_assert(NH % 2 == 0, "ping-pong unroll");

    const int tid  = threadIdx.x;
    const int lane = tid & 63;
    const int wv   = tid >> 6;           // 0..7
    const int wr   = wv >> 2, wc = wv & 3;

    // T1: bijective XCD swizzle (nwg divisible by 8 for all our shapes)
    const int bid = blockIdx.y * GX + blockIdx.x;
    const int nwg = GX * (int)gridDim.y;
    const int swz = (bid & 7) * (nwg >> 3) + (bid >> 3);
    const size_t row0 = (size_t)(swz / GX) * 256;
    const size_t col0 = (size_t)(swz % GX) * 256;

    // LDS: A ring = 4 x 16KB at +0 ; B ring = 4 x 16KB at +65536.
    // Half-slot: 256 rows x 64B. Chunk c (16B): row c>>2, pos c&3, holds
    // src k-chunk (c&3) ^ ((row>>1)&3)   [R3 swizzle, 0-conflict]
    const int cse = (((tid & 3) ^ ((tid >> 3) & 3)) << 3);  // src elem offset
    const unsigned short* ag = A + (row0 + (tid >> 2)) * (size_t)K + cse;
    const unsigned short* bg = W + (col0 + (tid >> 2)) * (size_t)K + cse;

    auto stage = [&](int hh) {           // 4 x gl_lds (A j0,j1 ; B j0,j1)
        char* dA = smem + (hh & 3) * 16384 + tid * 16;
        char* dB = dA + 65536;
        const unsigned short* a = ag + (size_t)hh * 32;
        const unsigned short* b = bg + (size_t)hh * 32;
        gl_lds16(a,                     dA);
        gl_lds16(a + (size_t)128 * K,   dA + 8192);
        gl_lds16(b,                     dB);
        gl_lds16(b + (size_t)128 * K,   dB + 8192);
    };

    // fragment reads: byte = row*64 + ((lane>>4) ^ ((row>>1)&3))*16
    const int ln15 = lane & 15;
    const int xo   = (((lane >> 4) ^ ((ln15 >> 1) & 3)) << 4);
    const int arow = wr * 128 + ln15;                       // + mi*16 (mi 0..7)
    const int brow = wc * 64 + ln15;                        // + nf*16 (nf 0..3)

#define LD(base, row) (*(const bf16x8*)((base) + (size_t)(row) * 64 + xo))

    f32x4 acc[8][4] = {};
    bf16x8 A0[4], B0[4], A1[4], B1[4], aH[4];

    // prologue: stage halves 0,1,2 ; certify stage(0) ; prefetch slot-0 quad-1
    stage(0); stage(1); stage(2);
    WAITVM(8);                           // stage(0) landed (1,2 in flight)
    SBAR();
#pragma unroll
    for (int mf = 0; mf < 4; ++mf) A0[mf] = LD(smem, arow + mf * 16);
#pragma unroll
    for (int nf = 0; nf < 4; ++nf) B0[nf] = LD(smem + 65536, brow + nf * 16);

    // one K-32 half: consume (pA,pB) on slot h, prefetch (nA,nB) from slot h+1
    auto half_body = [&](int h, bf16x8 (&pA)[4], bf16x8 (&pB)[4],
                         bf16x8 (&nA)[4], bf16x8 (&nB)[4]) {
        const char* cA  = smem + (h & 3) * 16384;
        const char* cB  = cA + 65536;
        const char* cAn = smem + ((h + 1) & 3) * 16384;
        const char* cBn = cAn + 65536;

        // top-of-half: certify through stage(h+1) (counted), then barrier
        if (h <= NH - 3) WAITVM(4);
        else             WAITVM(0);
        SBAR();

        // issue aH (slot h, rows 64..127); pA/pB in flight/landed
#pragma unroll
        for (int mf = 0; mf < 4; ++mf) aH[mf] = LD(cA, arow + 64 + mf * 16);
        WAITLG(4);                       // pA,pB certified; aH floats
        __builtin_amdgcn_s_setprio(1);
#pragma unroll
        for (int mf = 0; mf < 4; ++mf)
#pragma unroll
            for (int nf = 0; nf < 4; ++nf)
                acc[mf][nf] = __builtin_amdgcn_mfma_f32_16x16x32_bf16(
                    pA[mf], pB[nf], acc[mf][nf], 0, 0, 0);
        __builtin_amdgcn_s_setprio(0);

        // prefetch next half's quadrant-1 (slot h+1) + stage h+3
        if (h + 1 < NH) {
#pragma unroll
            for (int mf = 0; mf < 4; ++mf) nA[mf] = LD(cAn, arow + mf * 16);
#pragma unroll
            for (int nf = 0; nf < 4; ++nf) nB[nf] = LD(cBn, brow + nf * 16);
            SCHEDB();
        }
        if (h + 3 < NH) stage(h + 3);

        if (h + 1 < NH) WAITLG(8);       // aH certified; nA/nB float
        else            WAITLG(0);
        __builtin_amdgcn_s_setprio(1);
#pragma unroll
        for (int mf = 0; mf < 4; ++mf)
#pragma unroll
            for (int nf = 0; nf < 4; ++nf)
                acc[mf + 4][nf] = __builtin_amdgcn_mfma_f32_16x16x32_bf16(
                    aH[mf], pB[nf], acc[mf + 4][nf], 0, 0, 0);
        __builtin_amdgcn_s_setprio(0);
    };

    for (int h = 0; h < NH; h += 2) {
        half_body(h,     A0, B0, A1, B1);   // consume set0, fill set1
        half_body(h + 1, A1, B1, A0, B0);   // consume set1, fill set0
    }
#undef LD

    // epilogue: D layout col = lane&15, row = (lane>>4)*4 + reg
    const int lq = lane >> 4;
    float bv[4];
#pragma unroll
    for (int nf = 0; nf < 4; ++nf) bv[nf] = bias[col0 + wc * 64 + nf * 16 + ln15];

    if (EPI == 2) {
        // W interleaved by 16-col blocks: nf=2p -> s, nf=2p+1 -> t, same j.
        const float2* zin2 = (const float2*)zin;
        float2*       out2 = (float2*)outf;
#pragma unroll
        for (int mi = 0; mi < 8; ++mi) {
#pragma unroll
            for (int r = 0; r < 4; ++r) {
                const size_t row = row0 + wr * 128 + mi * 16 + lq * 4 + r;
                float sv = 0.f;
#pragma unroll
                for (int p = 0; p < 2; ++p) {
                    float s = acc[mi][2 * p][r] + bv[2 * p];
                    float t = acc[mi][2 * p + 1][r] + bv[2 * p + 1];
                    const size_t j = (col0 >> 1) + wc * 32 + p * 16 + ln15;
                    float2 zv = zin2[row * 512 + j];
                    float2 o; o.x = zv.x; o.y = zv.y * __expf(s) + t;
                    out2[row * 512 + j] = o;
                    sv += s;
                }
                sv += __shfl_xor(sv, 1, 64);
                sv += __shfl_xor(sv, 2, 64);
                sv += __shfl_xor(sv, 4, 64);
                sv += __shfl_xor(sv, 8, 64);
                if (ln15 == 0) atomicAdd(&ldout[row], sv);
            }
        }
    } else {
#pragma unroll
        for (int mi = 0; mi < 8; ++mi) {
#pragma unroll
            for (int r = 0; r < 4; ++r) {
                const size_t row = row0 + wr * 128 + mi * 16 + lq * 4 + r;
#pragma unroll
                for (int nf = 0; nf < 4; ++nf) {
                    const size_t col = col0 + wc * 64 + nf * 16 + ln15;
                    float v = acc[mi][nf][r] + bv[nf];
                    if (EPI == 0) {
                        float g = 0.5f * v * (1.0f + erff(v * 0.70710678118654752f));
                        outb[row * N + col] = f2bf(g);
                    } else {
                        outf[row * N + col] = v;
                    }
                }
            }
        }
    }
}

// One fused prep pass: W1/W2 cvt, W3 interleave-by-16 cvt, pack_even, b3i, ldout.
__global__ void prep_all(const float* __restrict__ W1, const float* __restrict__ W2,
                         const float* __restrict__ W3, const float* __restrict__ b3,
                         const float* __restrict__ z,  const float* __restrict__ ld,
                         unsigned short* __restrict__ w1b, unsigned short* __restrict__ w2b,
                         unsigned short* __restrict__ w3i, float* __restrict__ b3i,
                         unsigned short* __restrict__ zm,  float* __restrict__ ldout)
{
    constexpr int N1 = 2048 * 512 / 4;
    constexpr int N2 = 2048 * 2048 / 4;
    constexpr int N3 = 1024 * 2048 / 4;
    constexpr int N4 = 16384 * 1024 / 4;
    constexpr int N5 = 1024;
    constexpr int N6 = 16384;
    constexpr int TOT = N1 + N2 + N3 + N4 + N5 + N6;
    const int stride = gridDim.x * blockDim.x;
    for (int i = blockIdx.x * blockDim.x + threadIdx.x; i < TOT; i += stride) {
        int j = i;
        if (j < N1) {
            float4 v = ((const float4*)W1)[j];
            ((us4*)w1b)[j] = us4{ f2bf(v.x), f2bf(v.y), f2bf(v.z), f2bf(v.w) };
            continue;
        }
        j -= N1;
        if (j < N2) {
            float4 v = ((const float4*)W2)[j];
            ((us4*)w2b)[j] = us4{ f2bf(v.x), f2bf(v.y), f2bf(v.z), f2bf(v.w) };
            continue;
        }
        j -= N2;
        if (j < N3) {
            int row = j >> 9, c4 = j & 511;
            int q = row >> 5, u = row & 31;
            int srcrow = (u < 16) ? (q * 16 + u) : (512 + q * 16 + u - 16);
            float4 v = ((const float4*)W3)[(size_t)srcrow * 512 + c4];
            ((us4*)w3i)[j] = us4{ f2bf(v.x), f2bf(v.y), f2bf(v.z), f2bf(v.w) };
            continue;
        }
        j -= N3;
        if (j < N4) {
            float4 v = ((const float4*)z)[j];
            ((us2*)zm)[j] = us2{ f2bf(v.x), f2bf(v.z) };
            continue;
        }
        j -= N4;
        if (j < N5) {
            int q = j >> 5, u = j & 31;
            b3i[j] = b3[(u < 16) ? (q * 16 + u) : (512 + q * 16 + u - 16)];
            continue;
        }
        j -= N5;
        ldout[j] = ld[j];
    }
}

extern "C" void kernel_launch(void* const* d_in, const int* in_sizes, int n_in,
                              void* d_out, int out_size, void* d_ws, size_t ws_size,
                              hipStream_t stream)
{
    const float* z  = (const float*)d_in[0];
    const float* ld = (const float*)d_in[1];
    const float* W1 = (const float*)d_in[2];
    const float* b1 = (const float*)d_in[3];
    const float* W2 = (const float*)d_in[4];
    const float* b2 = (const float*)d_in[5];
    const float* W3 = (const float*)d_in[6];
    const float* b3 = (const float*)d_in[7];

    float* out   = (float*)d_out;
    float* zout  = out;
    float* ldout = out + (size_t)16384 * 1024;

    char* w = (char*)d_ws;
    unsigned short* zm  = (unsigned short*)w; w += (size_t)16384 * 512 * 2;
    unsigned short* w1b = (unsigned short*)w; w += (size_t)2048 * 512 * 2;
    unsigned short* w2b = (unsigned short*)w; w += (size_t)2048 * 2048 * 2;
    unsigned short* w3i = (unsigned short*)w; w += (size_t)1024 * 2048 * 2;
    unsigned short* h1  = (unsigned short*)w; w += (size_t)16384 * 2048 * 2;
    unsigned short* h2  = (unsigned short*)w; w += (size_t)16384 * 2048 * 2;
    float*          b3i = (float*)w;          w += 1024 * 4;

    (void)hipFuncSetAttribute((const void*)&gemm256<0, 512,  2048>,
                              hipFuncAttributeMaxDynamicSharedMemorySize, 131072);
    (void)hipFuncSetAttribute((const void*)&gemm256<0, 2048, 2048>,
                              hipFuncAttributeMaxDynamicSharedMemorySize, 131072);
    (void)hipFuncSetAttribute((const void*)&gemm256<2, 2048, 1024>,
                              hipFuncAttributeMaxDynamicSharedMemorySize, 131072);

    prep_all<<<2048, 256, 0, stream>>>(W1, W2, W3, b3, z, ld,
                                       w1b, w2b, w3i, b3i, zm, ldout);

    gemm256<0, 512,  2048><<<dim3(8, 64), 512, 131072, stream>>>(zm, w1b, b1, h1, nullptr, nullptr, nullptr);
    gemm256<0, 2048, 2048><<<dim3(8, 64), 512, 131072, stream>>>(h1, w2b, b2, h2, nullptr, nullptr, nullptr);
    gemm256<2, 2048, 1024><<<dim3(4, 64), 512, 131072, stream>>>(h2, w3i, b3i, nullptr, zout, z, ldout);
}